// Round 12
// baseline (1387.584 us; speedup 1.0000x reference)
//
#include <hip/hip_runtime.h>

// ---------------------------------------------------------------------------
// ZSSR involution net, fp32. Round 12: persistent 6-layer kernel.
// R10's t/e phase structure and band swizzle kept EXACTLY (212us build);
// the 12 t/e dispatches become phases of ONE 1024-WG persistent kernel with
// software grid barriers (co-residency: VGPR<=128 & LDS 28.6KB -> 4 WG/CU
// exactly => all 1024 resident). Dispatches 14 -> 3.
// Layout: x[4 g][136x136 padded px][16 ch] channel-last, 3-px zero border.
// ---------------------------------------------------------------------------

#define HH 130
#define SP 136               // padded row stride
#define PPL (SP*SP)          // 18496
#define GP (PPL*16)          // floats per group-plane
#define XBUF2 (4*GP)         // floats per feature buffer
#define OFF_TF (2*XBUF2)     // t-field: 16900*16 floats [px][16]
#define OFF_CNT (OFF_TF + 16900*16)   // barrier counter (1 uint)

// --- conv_in (3->64, 3x3, pad=2) + border zeroing + barrier-counter init ---
__global__ __launch_bounds__(256) void conv_in_kernel(
        const float* __restrict__ inf, const float* __restrict__ W,
        const float* __restrict__ b, float* __restrict__ x0,
        float* __restrict__ x1, unsigned* __restrict__ cnt) {
    const int tid = threadIdx.x;
    if (blockIdx.x == 0 && blockIdx.y == 0 && tid == 0) *cnt = 0u;
    if (blockIdx.x >= 67) {
        int idx = ((blockIdx.x - 67)*4 + blockIdx.y)*256 + tid;
        if (idx < 3192) {                      // 1596 border px * 2 buffers
            int bsel = idx & 1, e = idx >> 1;
            int r, c;
            if (e < 816) { r = e/136; c = e%136; if (r >= 3) r += 130; }
            else { int j = e-816; r = 3 + j/6; int m = j%6; c = (m<3)? m : m+130; }
            float* base = (bsel ? x1 : x0) + ((size_t)r*SP + c)*16;
            float4 z = make_float4(0.f,0.f,0.f,0.f);
            #pragma unroll
            for (int g2 = 0; g2 < 4; ++g2)
                #pragma unroll
                for (int q = 0; q < 4; ++q)
                    *(float4*)(base + (size_t)g2*GP + q*4) = z;
        }
        return;
    }
    __shared__ float wl[448];          // [16 ch][27 taps] + bias[16]
    const int g = blockIdx.y;
    for (int i = tid; i < 448; i += 256)
        wl[i] = (i < 432) ? W[g*432 + i] : b[g*16 + (i-432)];
    __syncthreads();
    int px = blockIdx.x*256 + tid;
    int pxc = px < 16900 ? px : 16899;
    int h = pxc/130, w = pxc%130;
    float xv[27];
    #pragma unroll
    for (int i = 0; i < 3; ++i)
      #pragma unroll
      for (int ky = 0; ky < 3; ++ky) {
        int y = h - 2 + ky;
        #pragma unroll
        for (int kx = 0; kx < 3; ++kx) {
            int xx = w - 2 + kx;
            float v = 0.f;
            if ((unsigned)y < 128u && (unsigned)xx < 128u)
                v = inf[i*16384 + y*128 + xx];
            xv[i*9 + ky*3 + kx] = v;
        }
      }
    float acc[16];
    #pragma unroll
    for (int c = 0; c < 16; ++c) {
        float a = wl[432 + c];
        #pragma unroll
        for (int t = 0; t < 27; ++t) a += wl[c*27 + t] * xv[t];
        acc[c] = a;
    }
    if (px < 16900) {
        float* dst = x0 + (size_t)g*GP + ((size_t)(h+3)*SP + (w+3))*16;
        #pragma unroll
        for (int q = 0; q < 4; ++q)
            *(float4*)(dst + q*4) =
                make_float4(acc[q*4], acc[q*4+1], acc[q*4+2], acc[q*4+3]);
    }
}

// --- software grid barrier (all 1024 WGs resident by construction) ---------
__device__ __forceinline__ void gbar(unsigned* cnt, unsigned target) {
    __syncthreads();
    if (threadIdx.x == 0) {
        __threadfence();                       // release this CU's stores
        atomicAdd(cnt, 1u);                    // device-scope by default
        while (__hip_atomic_load(cnt, __ATOMIC_RELAXED,
                                 __HIP_MEMORY_SCOPE_AGENT) < target)
            __builtin_amdgcn_s_sleep(8);
        __threadfence();                       // acquire: invalidate caches
    }
    __syncthreads();
}

// --- inv6_kernel: 6 involution layers, persistent, R10 phase bodies --------
// grid 1024. t-phase: WGs 0..295 (band = w&7, tile = w>>3). e-phase: slots
// s = w and (w<160) s = w+1024; band s&7 == w&7; (T,g) cover is exact 1:1.
// LDS: xl[4][14][17][4] 15232B + wl[49][68] 13328B = 28560B -> 4 WGs/CU.
__global__ __launch_bounds__(256, 4) void inv6_kernel(
        float* __restrict__ x0, float* __restrict__ x1,
        float* __restrict__ tf, unsigned* __restrict__ cnt,
        const float* __restrict__ redw,   // [6][16][64]
        const float* __restrict__ gamma,  // [6][16]
        const float* __restrict__ beta,   // [6][16]
        const float* __restrict__ spanw,  // [6][4 g][49 k][16 r]
        const float* __restrict__ spanb)  // [6][4 g][49]
{
    __shared__ float xl[4][14][17][4];
    __shared__ float wl[49][68];
    const int tid = threadIdx.x;
    const int w = blockIdx.x;
    unsigned bar = 0;
    float* cur = x0; float* nxt = x1;

    for (int l = 0; l < 6; ++l) {
        // ================= t phase (R10 t_kernel body) =================
        if (w < 296) {
            const int T = (w & 7)*37 + (w >> 3);
            if (T < 289) {
                const int ty = (T/17)*8, tx = (T%17)*8;
                const int lane = tid & 63;
                const int rq = __builtin_amdgcn_readfirstlane(tid >> 6);
                const int h = ty + (lane >> 3), ww = tx + (lane & 7);
                const int hc = h < HH ? h : HH-1, wc = ww < HH ? ww : HH-1;
                const float* xb = cur + ((size_t)(hc+3)*SP + (wc+3))*16;
                const float* rw = redw + l*1024 + rq*256;
                float a0=0.f, a1=0.f, a2=0.f, a3=0.f;
                #pragma unroll
                for (int g2 = 0; g2 < 4; ++g2) {
                    #pragma unroll
                    for (int q = 0; q < 4; ++q) {
                        float4 v = *(const float4*)(xb + (size_t)g2*GP + q*4);
                        int c = g2*16 + q*4;
                        a0 += rw[c]*v.x     + rw[c+1]*v.y   + rw[c+2]*v.z   + rw[c+3]*v.w;
                        a1 += rw[64+c]*v.x  + rw[65+c]*v.y  + rw[66+c]*v.z  + rw[67+c]*v.w;
                        a2 += rw[128+c]*v.x + rw[129+c]*v.y + rw[130+c]*v.z + rw[131+c]*v.w;
                        a3 += rw[192+c]*v.x + rw[193+c]*v.y + rw[194+c]*v.z + rw[195+c]*v.w;
                    }
                }
                if (h < HH && ww < HH) {
                    const float* gm = gamma + l*16;
                    const float* bt = beta  + l*16;
                    int r0 = rq*4;
                    float4 t4;
                    t4.x = fmaxf(gm[r0+0]*a0 + bt[r0+0], 0.f);
                    t4.y = fmaxf(gm[r0+1]*a1 + bt[r0+1], 0.f);
                    t4.z = fmaxf(gm[r0+2]*a2 + bt[r0+2], 0.f);
                    t4.w = fmaxf(gm[r0+3]*a3 + bt[r0+3], 0.f);
                    *(float4*)(tf + ((size_t)h*HH + ww)*16 + r0) = t4;
                }
            }
        }
        gbar(cnt, (++bar)*1024);

        // ================= e phase (R10 e_kernel body) =================
        for (int si = 0; si < 2; ++si) {
            if (si == 1 && w >= 160) break;
            const int s = w + si*1024;
            const int sslot = s >> 3;
            const int T = (s & 7)*37 + (sslot >> 2);
            __syncthreads();                   // LDS reuse guard (slot0->1)
            if (T >= 289) continue;
            const int g = sslot & 3;
            const int ty = (T/17)*8, tx = (T%17)*8;
            const int px = tid & 63;
            const int wv = __builtin_amdgcn_readfirstlane(tid >> 6);
            const int sr = px >> 3, sc = px & 7;

            // stage halo: 14x14 px, 4 quads (group g's 16 ch)
            for (int i = tid; i < 784; i += 256) {
                int q = i & 3, p = i >> 2;
                int r = p / 14, c = p % 14;
                int gr = ty + r, gc = tx + c;
                gr = gr < SP ? gr : SP-1;      // clamp lands in zero border
                gc = gc < SP ? gc : SP-1;
                float4 v = *(const float4*)(cur + (size_t)g*GP
                                            + ((size_t)gr*SP + gc)*16 + q*4);
                *(float4*)&xl[q][r][c][0] = v;
            }

            // w-gen: lane = pixel, wave = k-chunk (13/12/12/12)
            {
                const int hh = min(ty + sr, HH-1), ww = min(tx + sc, HH-1);
                const float* tp = tf + ((size_t)hh*HH + ww)*16;
                float t16[16];
                #pragma unroll
                for (int q = 0; q < 4; ++q) {
                    float4 v = *(const float4*)(tp + q*4);
                    t16[q*4]=v.x; t16[q*4+1]=v.y; t16[q*4+2]=v.z; t16[q*4+3]=v.w;
                }
                const float* sw = spanw + l*3136 + g*784;  // wave-uniform
                const float* sb = spanb + l*196  + g*49;
                const int k0 = wv ? (wv*12 + 1) : 0;
                #pragma unroll
                for (int j = 0; j < 12; ++j) {
                    int k = k0 + j;
                    float a = sb[k];
                    #pragma unroll
                    for (int r = 0; r < 16; ++r) a += sw[k*16 + r] * t16[r];
                    wl[k][px] = a;
                }
                if (wv == 0) {
                    float a = sb[12];
                    #pragma unroll
                    for (int r = 0; r < 16; ++r) a += sw[12*16 + r] * t16[r];
                    wl[12][px] = a;
                }
            }
            __syncthreads();

            // einsum: 49 taps x 4 channels (wave's quad), all LDS
            const int cq = wv;
            float4 acc = make_float4(0.f, 0.f, 0.f, 0.f);
            #pragma unroll
            for (int i = 0; i < 7; ++i)
                #pragma unroll
                for (int j = 0; j < 7; ++j) {
                    float4 xv = *(const float4*)&xl[cq][sr + i][sc + j][0];
                    float wk = wl[i*7 + j][px];
                    acc.x += wk*xv.x; acc.y += wk*xv.y;
                    acc.z += wk*xv.z; acc.w += wk*xv.w;
                }

            const int h = ty + sr, ww = tx + sc;
            if (h < HH && ww < HH) {
                float4 o;
                o.x = fmaxf(acc.x, 0.f); o.y = fmaxf(acc.y, 0.f);
                o.z = fmaxf(acc.z, 0.f); o.w = fmaxf(acc.w, 0.f);
                *(float4*)(nxt + (size_t)g*GP
                           + ((size_t)(h+3)*SP + (ww+3))*16 + cq*4) = o;
            }
        }
        if (l < 5) gbar(cnt, (++bar)*1024);
        float* tm = cur; cur = nxt; nxt = tm;
    }
}

// --- conv_out (64->12, 3x3 valid) + PixelShuffle(2) ------------------------
__global__ __launch_bounds__(256) void conv_out_ps_kernel(
        const float* __restrict__ x, const float* __restrict__ W,
        const float* __restrict__ b, float* __restrict__ out)
{
    __shared__ float xh[64*120];   // [c][10 r][12 cl]
    __shared__ float wl[6912];     // 12*64*9
    const int tid = threadIdx.x;
    const int ty = blockIdx.y*8, tx = blockIdx.x*8;

    for (int idx = tid; idx < 6912; idx += 256) wl[idx] = W[idx];
    for (int idx = tid; idx < 1600; idx += 256) {
        int g = idx/400, rem = idx%400;
        int p100 = rem>>2, q = rem&3;
        int r = p100/10, cl = p100%10;
        float4 v = *(const float4*)(x + (size_t)g*GP
                     + ((size_t)(ty + r + 3)*SP + tx + cl + 3)*16 + q*4);
        int c0 = g*16 + q*4;
        xh[(c0+0)*120 + r*12 + cl] = v.x;
        xh[(c0+1)*120 + r*12 + cl] = v.y;
        xh[(c0+2)*120 + r*12 + cl] = v.z;
        xh[(c0+3)*120 + r*12 + cl] = v.w;
    }
    __syncthreads();

    const int wave = __builtin_amdgcn_readfirstlane(tid >> 6);
    const int lane = tid & 63;
    const int s = lane >> 2, cq = lane & 3;
    const int sr = s >> 1, pc0 = (s & 1)*4;
    float acc[3][4] = {};

    for (int c = cq*16; c < cq*16 + 16; ++c) {
        #pragma unroll
        for (int ky = 0; ky < 3; ++ky) {
            const float* xb = &xh[c*120 + (sr + ky)*12 + pc0];
            float4 xa = *(const float4*)xb;
            float2 xm = *(const float2*)(xb + 4);
            float xr[6] = {xa.x, xa.y, xa.z, xa.w, xm.x, xm.y};
            #pragma unroll
            for (int oj = 0; oj < 3; ++oj) {
                const float* wp = &wl[((wave*3 + oj)*64 + c)*9 + ky*3];
                #pragma unroll
                for (int kx = 0; kx < 3; ++kx) {
                    float wv = wp[kx];
                    #pragma unroll
                    for (int q = 0; q < 4; ++q)
                        acc[oj][q] += wv * xr[kx + q];
                }
            }
        }
    }

    #pragma unroll
    for (int oj = 0; oj < 3; ++oj)
        #pragma unroll
        for (int q = 0; q < 4; ++q) {
            float v = acc[oj][q];
            v += __shfl_xor(v, 1, 64);
            v += __shfl_xor(v, 2, 64);
            acc[oj][q] = v;
        }

    if (cq == 0) {
        #pragma unroll
        for (int oj = 0; oj < 3; ++oj) {
            int o = wave*3 + oj;
            float bo = b[o];
            int c3 = o >> 2, r = (o >> 1) & 1, s2 = o & 1;
            int h = ty + sr;
            #pragma unroll
            for (int q = 0; q < 4; ++q) {
                int w = tx + pc0 + q;
                out[c3*65536 + (2*h + r)*256 + 2*w + s2] = acc[oj][q] + bo;
            }
        }
    }
}

// ---------------------------------------------------------------------------
extern "C" void kernel_launch(void* const* d_in, const int* in_sizes, int n_in,
                              void* d_out, int out_size, void* d_ws, size_t ws_size,
                              hipStream_t stream) {
    const float* inf   = (const float*)d_in[0];
    const float* cinw  = (const float*)d_in[1];
    const float* cinb  = (const float*)d_in[2];
    const float* redw  = (const float*)d_in[3];
    const float* gam   = (const float*)d_in[4];
    const float* bet   = (const float*)d_in[5];
    const float* spw   = (const float*)d_in[6];
    const float* spb   = (const float*)d_in[7];
    const float* cow   = (const float*)d_in[8];
    const float* cob   = (const float*)d_in[9];

    float* ws = (float*)d_ws;
    float* x0 = ws;
    float* x1 = ws + XBUF2;
    float* tfield = ws + OFF_TF;
    unsigned* cnt = (unsigned*)(ws + OFF_CNT);

    conv_in_kernel<<<dim3(80, 4), 256, 0, stream>>>(
        inf, cinw, cinb, x0, x1, cnt);

    inv6_kernel<<<1024, 256, 0, stream>>>(
        x0, x1, tfield, cnt, redw, gam, bet, spw, spb);

    conv_out_ps_kernel<<<dim3(16, 16), 256, 0, stream>>>(
        x0, cow, cob, (float*)d_out);   // 6 layers: x0->x1->...->x0 (even)
}

// Round 13
// 330.184 us; speedup vs baseline: 4.2025x; 4.2025x over previous
//
#include <hip/hip_runtime.h>

// ---------------------------------------------------------------------------
// ZSSR involution net, fp32. Round 13 = R10 (212us) minus the 6 t_kernels.
// Next-layer t is accumulated INSIDE e_kernel: t stored as RAW sums (BN+ReLU
// applied by consumer => sum stays linear => atomicAdd-composable). Each e-WG
// (T,g) reduces its group's 16 output ch into LDS (ds_add), then 4 global
// atomicAdds/thread into the next t-buffer. 3 rotating t-buffers handle
// zeroing race-free (read l%3, acc (l+1)%3, zero (l+2)%3).
// Dispatches 14 -> 9. Band swizzle (wid&7 = XCD) kept everywhere.
// Layout: x[4 g][136x136 padded px][16 ch] channel-last, 3-px zero border.
// ---------------------------------------------------------------------------

#define HH 130
#define SP 136               // padded row stride
#define PPL (SP*SP)          // 18496
#define GP (PPL*16)          // floats per group-plane
#define XBUF2 (4*GP)         // floats per feature buffer
#define TFSZ (16900*16)      // one t-buffer: [px][16] raw sums
#define OFF_T0 (2*XBUF2)
#define OFF_T1 (OFF_T0 + TFSZ)
#define OFF_T2 (OFF_T1 + TFSZ)

// --- conv_in (3->64, 3x3, pad=2) + border zeroing of both ping-pong bufs ---
__global__ __launch_bounds__(256) void conv_in_kernel(
        const float* __restrict__ inf, const float* __restrict__ W,
        const float* __restrict__ b, float* __restrict__ x0,
        float* __restrict__ x1) {
    const int tid = threadIdx.x;
    if (blockIdx.x >= 67) {
        int idx = ((blockIdx.x - 67)*4 + blockIdx.y)*256 + tid;
        if (idx < 3192) {                      // 1596 border px * 2 buffers
            int bsel = idx & 1, e = idx >> 1;
            int r, c;
            if (e < 816) { r = e/136; c = e%136; if (r >= 3) r += 130; }
            else { int j = e-816; r = 3 + j/6; int m = j%6; c = (m<3)? m : m+130; }
            float* base = (bsel ? x1 : x0) + ((size_t)r*SP + c)*16;
            float4 z = make_float4(0.f,0.f,0.f,0.f);
            #pragma unroll
            for (int g2 = 0; g2 < 4; ++g2)
                #pragma unroll
                for (int q = 0; q < 4; ++q)
                    *(float4*)(base + (size_t)g2*GP + q*4) = z;
        }
        return;
    }
    __shared__ float wl[448];          // [16 ch][27 taps] + bias[16]
    const int g = blockIdx.y;
    for (int i = tid; i < 448; i += 256)
        wl[i] = (i < 432) ? W[g*432 + i] : b[g*16 + (i-432)];
    __syncthreads();
    int px = blockIdx.x*256 + tid;
    int pxc = px < 16900 ? px : 16899;
    int h = pxc/130, w = pxc%130;
    float xv[27];
    #pragma unroll
    for (int i = 0; i < 3; ++i)
      #pragma unroll
      for (int ky = 0; ky < 3; ++ky) {
        int y = h - 2 + ky;
        #pragma unroll
        for (int kx = 0; kx < 3; ++kx) {
            int xx = w - 2 + kx;
            float v = 0.f;
            if ((unsigned)y < 128u && (unsigned)xx < 128u)
                v = inf[i*16384 + y*128 + xx];
            xv[i*9 + ky*3 + kx] = v;
        }
      }
    float acc[16];
    #pragma unroll
    for (int c = 0; c < 16; ++c) {
        float a = wl[432 + c];
        #pragma unroll
        for (int t = 0; t < 27; ++t) a += wl[c*27 + t] * xv[t];
        acc[c] = a;
    }
    if (px < 16900) {
        float* dst = x0 + (size_t)g*GP + ((size_t)(h+3)*SP + (w+3))*16;
        #pragma unroll
        for (int q = 0; q < 4; ++q)
            *(float4*)(dst + q*4) =
                make_float4(acc[q*4], acc[q*4+1], acc[q*4+2], acc[q*4+3]);
    }
}

// --- t0_kernel: RAW t sums for layer 0 into tb0; also zero tb1 -------------
// grid 296: wid&7 = band, wid>>3 = slot. 256 thr = 64px x 4 rq-waves.
__global__ __launch_bounds__(256) void t0_kernel(
        const float* __restrict__ x, float* __restrict__ tb0,
        float* __restrict__ tb1,
        const float* __restrict__ redw)   // [16][64], layer 0
{
    const int wid = blockIdx.x;
    const int T = (wid & 7)*37 + (wid >> 3);
    if (T >= 289) return;
    const int ty = (T/17)*8, tx = (T%17)*8;
    const int tid = threadIdx.x;

    // zero tb1 tile region (1 float4/thread)
    {
        int zr = tid >> 5, zc4 = tid & 31;
        int zh = ty + zr, zw = tx + (zc4 >> 2);
        if (zh < HH && zw < HH)
            *(float4*)(tb1 + ((size_t)zh*HH + zw)*16 + (zc4 & 3)*4) =
                make_float4(0.f,0.f,0.f,0.f);
    }

    const int lane = tid & 63;
    const int rq = __builtin_amdgcn_readfirstlane(tid >> 6);
    const int h = ty + (lane >> 3), w = tx + (lane & 7);
    const int hc = h < HH ? h : HH-1, wc = w < HH ? w : HH-1;

    const float* xb = x + ((size_t)(hc+3)*SP + (wc+3))*16;
    const float* rw = redw + rq*4*64;
    float a0=0.f, a1=0.f, a2=0.f, a3=0.f;
    #pragma unroll
    for (int g2 = 0; g2 < 4; ++g2) {
        #pragma unroll
        for (int q = 0; q < 4; ++q) {
            float4 v = *(const float4*)(xb + (size_t)g2*GP + q*4);
            int c = g2*16 + q*4;
            a0 += rw[c]*v.x     + rw[c+1]*v.y   + rw[c+2]*v.z   + rw[c+3]*v.w;
            a1 += rw[64+c]*v.x  + rw[65+c]*v.y  + rw[66+c]*v.z  + rw[67+c]*v.w;
            a2 += rw[128+c]*v.x + rw[129+c]*v.y + rw[130+c]*v.z + rw[131+c]*v.w;
            a3 += rw[192+c]*v.x + rw[193+c]*v.y + rw[194+c]*v.z + rw[195+c]*v.w;
        }
    }
    if (h < HH && w < HH) {
        int r0 = rq*4;
        *(float4*)(tb0 + ((size_t)h*HH + w)*16 + r0) =
            make_float4(a0, a1, a2, a3);   // RAW sums (BN in consumer)
    }
}

// --- e_kernel v9 = R10 e v8 + BN-on-read + fused next-t accumulation -------
// grid 1184: wid&7 = band, slot = wid>>3; T = band*37+(slot>>2), g = slot&3.
// LDS: xl 15232B + wl 13328B + sl[64][16] 4096B = 32656B -> 4 WG/CU.
__global__ __launch_bounds__(256, 4) void e_kernel(
        const float* __restrict__ x,
        const float* __restrict__ tread,  // raw t sums, this layer
        float* __restrict__ tacc,         // raw t sums, next layer (atomic)
        float* __restrict__ tzero,        // buffer to zero for layer l+2
        const float* __restrict__ gamma, const float* __restrict__ beta,
        const float* __restrict__ spanw,  // [4 g][49 k][16 r]
        const float* __restrict__ spanb,  // [4 g][49]
        const float* __restrict__ redwn,  // [16][64] next layer (or x for l=5)
        float* __restrict__ xout,
        const int doNext)
{
    __shared__ float xl[4][14][17][4];
    __shared__ float wl[49][68];
    __shared__ float sl[64][16];
    const int wid = blockIdx.x;
    const int slot = wid >> 3;
    const int T = (wid & 7)*37 + (slot >> 2);
    if (T >= 289) return;
    const int g = slot & 3;
    const int ty = (T/17)*8, tx = (T%17)*8;
    const int tid = threadIdx.x;
    const int px = tid & 63;
    const int wv = __builtin_amdgcn_readfirstlane(tid >> 6);
    const int sr = px >> 3, sc = px & 7;

    // ---- stage halo + zero sl + zero tzero tile region ----
    for (int i = tid; i < 784; i += 256) {
        int q = i & 3, p = i >> 2;
        int r = p / 14, c = p % 14;
        int gr = ty + r, gc = tx + c;
        gr = gr < SP ? gr : SP-1;          // clamp lands in zero border
        gc = gc < SP ? gc : SP-1;
        float4 v = *(const float4*)(x + (size_t)g*GP
                                    + ((size_t)gr*SP + gc)*16 + q*4);
        *(float4*)&xl[q][r][c][0] = v;
    }
    if (doNext) {
        *(float4*)&sl[tid >> 2][(tid & 3)*4] = make_float4(0.f,0.f,0.f,0.f);
        int zr = tid >> 5, zc4 = tid & 31;
        int zh = ty + zr, zw = tx + (zc4 >> 2);
        if (zh < HH && zw < HH)
            *(float4*)(tzero + ((size_t)zh*HH + zw)*16 + (zc4 & 3)*4) =
                make_float4(0.f,0.f,0.f,0.f);
    }

    // ---- w-gen: lane = pixel, wave = k-chunk; BN+ReLU applied on read ----
    {
        const int hh = min(ty + sr, HH-1), ww = min(tx + sc, HH-1);
        const float* tp = tread + ((size_t)hh*HH + ww)*16;
        float t16[16];
        #pragma unroll
        for (int q = 0; q < 4; ++q) {
            float4 v = *(const float4*)(tp + q*4);
            t16[q*4+0] = fmaxf(gamma[q*4+0]*v.x + beta[q*4+0], 0.f);
            t16[q*4+1] = fmaxf(gamma[q*4+1]*v.y + beta[q*4+1], 0.f);
            t16[q*4+2] = fmaxf(gamma[q*4+2]*v.z + beta[q*4+2], 0.f);
            t16[q*4+3] = fmaxf(gamma[q*4+3]*v.w + beta[q*4+3], 0.f);
        }
        const float* sw = spanw + g*784;   // k,r wave-uniform -> s_load
        const float* sb = spanb + g*49;
        const int k0 = wv ? (wv*12 + 1) : 0;
        #pragma unroll
        for (int j = 0; j < 12; ++j) {
            int k = k0 + j;
            float a = sb[k];
            #pragma unroll
            for (int r = 0; r < 16; ++r) a += sw[k*16 + r] * t16[r];
            wl[k][px] = a;
        }
        if (wv == 0) {
            float a = sb[12];
            #pragma unroll
            for (int r = 0; r < 16; ++r) a += sw[12*16 + r] * t16[r];
            wl[12][px] = a;
        }
    }
    __syncthreads();

    // ---- einsum: 49 taps x 4 channels (wave's quad), all LDS ----
    const int cq = wv;
    float4 acc = make_float4(0.f, 0.f, 0.f, 0.f);
    #pragma unroll
    for (int i = 0; i < 7; ++i)
        #pragma unroll
        for (int j = 0; j < 7; ++j) {
            float4 xv = *(const float4*)&xl[cq][sr + i][sc + j][0];
            float wk = wl[i*7 + j][px];
            acc.x += wk*xv.x; acc.y += wk*xv.y;
            acc.z += wk*xv.z; acc.w += wk*xv.w;
        }

    const int h = ty + sr, ww2 = tx + sc;
    const bool valid = (h < HH) && (ww2 < HH);
    float4 o = make_float4(fmaxf(acc.x,0.f), fmaxf(acc.y,0.f),
                           fmaxf(acc.z,0.f), fmaxf(acc.w,0.f));
    if (valid)
        *(float4*)(xout + (size_t)g*GP
                   + ((size_t)(h+3)*SP + (ww2+3))*16 + cq*4) = o;

    // ---- fused next-layer t partial: group-local LDS reduce + global add --
    if (doNext) {
        if (valid) {
            const int c0 = g*16 + cq*4;        // wave-uniform -> s_load redwn
            #pragma unroll
            for (int r = 0; r < 16; ++r) {
                float p = redwn[r*64 + c0]*o.x + redwn[r*64 + c0+1]*o.y
                        + redwn[r*64 + c0+2]*o.z + redwn[r*64 + c0+3]*o.w;
                atomicAdd(&sl[px][r], p);
            }
        }
        __syncthreads();
        int px2 = tid >> 2, r0 = (tid & 3)*4;
        int h2 = ty + (px2 >> 3), w2 = tx + (px2 & 7);
        if (h2 < HH && w2 < HH) {
            float* dt = tacc + ((size_t)h2*HH + w2)*16 + r0;
            atomicAdd(dt+0, sl[px2][r0+0]);
            atomicAdd(dt+1, sl[px2][r0+1]);
            atomicAdd(dt+2, sl[px2][r0+2]);
            atomicAdd(dt+3, sl[px2][r0+3]);
        }
    }
}

// --- conv_out (64->12, 3x3 valid) + PixelShuffle(2) ------------------------
__global__ __launch_bounds__(256) void conv_out_ps_kernel(
        const float* __restrict__ x, const float* __restrict__ W,
        const float* __restrict__ b, float* __restrict__ out)
{
    __shared__ float xh[64*120];   // [c][10 r][12 cl]
    __shared__ float wl[6912];     // 12*64*9
    const int tid = threadIdx.x;
    const int ty = blockIdx.y*8, tx = blockIdx.x*8;

    for (int idx = tid; idx < 6912; idx += 256) wl[idx] = W[idx];
    for (int idx = tid; idx < 1600; idx += 256) {
        int g = idx/400, rem = idx%400;
        int p100 = rem>>2, q = rem&3;
        int r = p100/10, cl = p100%10;
        float4 v = *(const float4*)(x + (size_t)g*GP
                     + ((size_t)(ty + r + 3)*SP + tx + cl + 3)*16 + q*4);
        int c0 = g*16 + q*4;
        xh[(c0+0)*120 + r*12 + cl] = v.x;
        xh[(c0+1)*120 + r*12 + cl] = v.y;
        xh[(c0+2)*120 + r*12 + cl] = v.z;
        xh[(c0+3)*120 + r*12 + cl] = v.w;
    }
    __syncthreads();

    const int wave = __builtin_amdgcn_readfirstlane(tid >> 6);
    const int lane = tid & 63;
    const int s = lane >> 2, cq = lane & 3;
    const int sr = s >> 1, pc0 = (s & 1)*4;
    float acc[3][4] = {};

    for (int c = cq*16; c < cq*16 + 16; ++c) {
        #pragma unroll
        for (int ky = 0; ky < 3; ++ky) {
            const float* xb = &xh[c*120 + (sr + ky)*12 + pc0];
            float4 xa = *(const float4*)xb;
            float2 xm = *(const float2*)(xb + 4);
            float xr[6] = {xa.x, xa.y, xa.z, xa.w, xm.x, xm.y};
            #pragma unroll
            for (int oj = 0; oj < 3; ++oj) {
                const float* wp = &wl[((wave*3 + oj)*64 + c)*9 + ky*3];
                #pragma unroll
                for (int kx = 0; kx < 3; ++kx) {
                    float wv = wp[kx];
                    #pragma unroll
                    for (int q = 0; q < 4; ++q)
                        acc[oj][q] += wv * xr[kx + q];
                }
            }
        }
    }

    #pragma unroll
    for (int oj = 0; oj < 3; ++oj)
        #pragma unroll
        for (int q = 0; q < 4; ++q) {
            float v = acc[oj][q];
            v += __shfl_xor(v, 1, 64);
            v += __shfl_xor(v, 2, 64);
            acc[oj][q] = v;
        }

    if (cq == 0) {
        #pragma unroll
        for (int oj = 0; oj < 3; ++oj) {
            int o = wave*3 + oj;
            float bo = b[o];
            int c3 = o >> 2, r = (o >> 1) & 1, s2 = o & 1;
            int h = ty + sr;
            #pragma unroll
            for (int q = 0; q < 4; ++q) {
                int w = tx + pc0 + q;
                out[c3*65536 + (2*h + r)*256 + 2*w + s2] = acc[oj][q] + bo;
            }
        }
    }
}

// ---------------------------------------------------------------------------
extern "C" void kernel_launch(void* const* d_in, const int* in_sizes, int n_in,
                              void* d_out, int out_size, void* d_ws, size_t ws_size,
                              hipStream_t stream) {
    const float* inf   = (const float*)d_in[0];
    const float* cinw  = (const float*)d_in[1];
    const float* cinb  = (const float*)d_in[2];
    const float* redw  = (const float*)d_in[3];
    const float* gam   = (const float*)d_in[4];
    const float* bet   = (const float*)d_in[5];
    const float* spw   = (const float*)d_in[6];
    const float* spb   = (const float*)d_in[7];
    const float* cow   = (const float*)d_in[8];
    const float* cob   = (const float*)d_in[9];

    float* ws = (float*)d_ws;
    float* x0 = ws;
    float* x1 = ws + XBUF2;
    float* tb[3] = { ws + OFF_T0, ws + OFF_T1, ws + OFF_T2 };

    conv_in_kernel<<<dim3(80, 4), 256, 0, stream>>>(inf, cinw, cinb, x0, x1);

    t0_kernel<<<296, 256, 0, stream>>>(x0, tb[0], tb[1], redw);

    float* cur = x0; float* nxt = x1;
    for (int l = 0; l < 6; ++l) {
        const int doNext = (l < 5);
        e_kernel<<<1184, 256, 0, stream>>>(
            cur, tb[l % 3], tb[(l+1) % 3], tb[(l+2) % 3],
            gam + l*16, bet + l*16,
            spw + l*3136, spb + l*196,
            redw + (doNext ? (l+1)*1024 : 0),
            nxt, doNext);
        float* t = cur; cur = nxt; nxt = t;
    }

    conv_out_ps_kernel<<<dim3(16, 16), 256, 0, stream>>>(
        cur, cow, cob, (float*)d_out);
}

// Round 14
// 192.777 us; speedup vs baseline: 7.1979x; 1.7128x over previous
//
#include <hip/hip_runtime.h>

// ---------------------------------------------------------------------------
// ZSSR involution net, fp32. Round 14 = R10 (212us) with t-kernels fused out
// via PRIVATE per-group partial buffers (plain stores, NO atomics).
// Producer e-WG (T,g): after einsum, stages o in dead xl LDS (stride 17),
// reduces its group's 16 ch -> tpart[g][px][16] (unique writer, float4).
// Consumer w-gen: t16 = BN(sum of 4 partials). conv_in emits layer-0 partials
// directly (each thread owns all 16 ch of its group). Dispatches 14 -> 8.
// Band swizzle (wid&7 = XCD) kept. Layout: x[4 g][136x136 px][16 ch],
// channel-last, 3-px zero border.
// ---------------------------------------------------------------------------

#define HH 130
#define SP 136               // padded row stride
#define PPL (SP*SP)          // 18496
#define GP (PPL*16)          // floats per group-plane
#define XBUF2 (4*GP)         // floats per feature buffer
#define TP1 (16900*16)       // one group-partial buffer [px][16]
#define OFF_TA (2*XBUF2)             // set A: 4 buffers
#define OFF_TB (OFF_TA + 4*TP1)      // set B: 4 buffers

// --- conv_in (3->64, 3x3, pad=2) + border zeroing + layer-0 t partials -----
__global__ __launch_bounds__(256) void conv_in_kernel(
        const float* __restrict__ inf, const float* __restrict__ W,
        const float* __restrict__ b, float* __restrict__ x0,
        float* __restrict__ x1, float* __restrict__ tpA,
        const float* __restrict__ redw0) {   // [16][64] layer 0
    const int tid = threadIdx.x;
    if (blockIdx.x >= 67) {
        int idx = ((blockIdx.x - 67)*4 + blockIdx.y)*256 + tid;
        if (idx < 3192) {                      // 1596 border px * 2 buffers
            int bsel = idx & 1, e = idx >> 1;
            int r, c;
            if (e < 816) { r = e/136; c = e%136; if (r >= 3) r += 130; }
            else { int j = e-816; r = 3 + j/6; int m = j%6; c = (m<3)? m : m+130; }
            float* base = (bsel ? x1 : x0) + ((size_t)r*SP + c)*16;
            float4 z = make_float4(0.f,0.f,0.f,0.f);
            #pragma unroll
            for (int g2 = 0; g2 < 4; ++g2)
                #pragma unroll
                for (int q = 0; q < 4; ++q)
                    *(float4*)(base + (size_t)g2*GP + q*4) = z;
        }
        return;
    }
    __shared__ float wl[448];          // [16 ch][27 taps] + bias[16]
    const int g = blockIdx.y;
    for (int i = tid; i < 448; i += 256)
        wl[i] = (i < 432) ? W[g*432 + i] : b[g*16 + (i-432)];
    __syncthreads();
    int px = blockIdx.x*256 + tid;
    int pxc = px < 16900 ? px : 16899;
    int h = pxc/130, w = pxc%130;
    float xv[27];
    #pragma unroll
    for (int i = 0; i < 3; ++i)
      #pragma unroll
      for (int ky = 0; ky < 3; ++ky) {
        int y = h - 2 + ky;
        #pragma unroll
        for (int kx = 0; kx < 3; ++kx) {
            int xx = w - 2 + kx;
            float v = 0.f;
            if ((unsigned)y < 128u && (unsigned)xx < 128u)
                v = inf[i*16384 + y*128 + xx];
            xv[i*9 + ky*3 + kx] = v;
        }
      }
    float acc[16];
    #pragma unroll
    for (int c = 0; c < 16; ++c) {
        float a = wl[432 + c];
        #pragma unroll
        for (int t = 0; t < 27; ++t) a += wl[c*27 + t] * xv[t];
        acc[c] = a;
    }
    if (px < 16900) {
        float* dst = x0 + (size_t)g*GP + ((size_t)(h+3)*SP + (w+3))*16;
        #pragma unroll
        for (int q = 0; q < 4; ++q)
            *(float4*)(dst + q*4) =
                make_float4(acc[q*4], acc[q*4+1], acc[q*4+2], acc[q*4+3]);
        // layer-0 t partial for group g (thread owns all 16 ch; s_load redw0)
        float* td = tpA + (size_t)g*TP1 + (size_t)px*16;
        #pragma unroll
        for (int rq = 0; rq < 4; ++rq) {
            float4 pv;
            float p0=0.f, p1=0.f, p2=0.f, p3=0.f;
            #pragma unroll
            for (int j = 0; j < 16; ++j) {
                float a = acc[j];
                p0 += redw0[(rq*4+0)*64 + g*16 + j]*a;
                p1 += redw0[(rq*4+1)*64 + g*16 + j]*a;
                p2 += redw0[(rq*4+2)*64 + g*16 + j]*a;
                p3 += redw0[(rq*4+3)*64 + g*16 + j]*a;
            }
            pv.x=p0; pv.y=p1; pv.z=p2; pv.w=p3;
            *(float4*)(td + rq*4) = pv;
        }
    }
}

// --- e_kernel v10 = R10 e v8 + partial-sum t on read + partial t emit ------
// grid 1184: wid&7 = band, slot = wid>>3; T = band*37+(slot>>2), g = slot&3.
// LDS: xl[4][14][17][4] 15232B + wl[49][68] 13328B = 28560B -> 4 WG/CU.
// Epilogue reuses dead xl as ol[64][17] to reduce group t partial, then one
// float4 store per (px,rq) thread into twrite[g] (unique writer, no atomics).
__global__ __launch_bounds__(256, 4) void e_kernel(
        const float* __restrict__ x,
        const float* __restrict__ tread,  // 4 partial bufs, this layer
        float* __restrict__ twrite,       // 4 partial bufs, next layer
        const float* __restrict__ gamma, const float* __restrict__ beta,
        const float* __restrict__ spanw,  // [4 g][49 k][16 r]
        const float* __restrict__ spanb,  // [4 g][49]
        const float* __restrict__ redwn,  // [16][64] next layer
        float* __restrict__ xout,
        const int doNext)
{
    __shared__ float xl[4][14][17][4];
    __shared__ float wl[49][68];
    const int wid = blockIdx.x;
    const int slot = wid >> 3;
    const int T = (wid & 7)*37 + (slot >> 2);
    if (T >= 289) return;
    const int g = slot & 3;
    const int ty = (T/17)*8, tx = (T%17)*8;
    const int tid = threadIdx.x;
    const int px = tid & 63;
    const int wv = __builtin_amdgcn_readfirstlane(tid >> 6);
    const int sr = px >> 3, sc = px & 7;

    // ---- stage halo: 14x14 px, 4 quads (group g's 16 ch) ----
    for (int i = tid; i < 784; i += 256) {
        int q = i & 3, p = i >> 2;
        int r = p / 14, c = p % 14;
        int gr = ty + r, gc = tx + c;
        gr = gr < SP ? gr : SP-1;          // clamp lands in zero border
        gc = gc < SP ? gc : SP-1;
        float4 v = *(const float4*)(x + (size_t)g*GP
                                    + ((size_t)gr*SP + gc)*16 + q*4);
        *(float4*)&xl[q][r][c][0] = v;
    }

    // ---- w-gen: lane = pixel, wave = k-chunk; t = BN(sum of 4 partials) ---
    {
        const int hh = min(ty + sr, HH-1), ww = min(tx + sc, HH-1);
        const size_t toff = ((size_t)hh*HH + ww)*16;
        float4 v0 = make_float4(0,0,0,0), v1 = v0, v2 = v0, v3 = v0;
        #pragma unroll
        for (int gg = 0; gg < 4; ++gg) {
            const float* tp = tread + (size_t)gg*TP1 + toff;
            float4 a0 = *(const float4*)(tp);
            float4 a1 = *(const float4*)(tp + 4);
            float4 a2 = *(const float4*)(tp + 8);
            float4 a3 = *(const float4*)(tp + 12);
            v0.x+=a0.x; v0.y+=a0.y; v0.z+=a0.z; v0.w+=a0.w;
            v1.x+=a1.x; v1.y+=a1.y; v1.z+=a1.z; v1.w+=a1.w;
            v2.x+=a2.x; v2.y+=a2.y; v2.z+=a2.z; v2.w+=a2.w;
            v3.x+=a3.x; v3.y+=a3.y; v3.z+=a3.z; v3.w+=a3.w;
        }
        float t16[16];
        t16[0]  = fmaxf(gamma[0] *v0.x + beta[0] , 0.f);
        t16[1]  = fmaxf(gamma[1] *v0.y + beta[1] , 0.f);
        t16[2]  = fmaxf(gamma[2] *v0.z + beta[2] , 0.f);
        t16[3]  = fmaxf(gamma[3] *v0.w + beta[3] , 0.f);
        t16[4]  = fmaxf(gamma[4] *v1.x + beta[4] , 0.f);
        t16[5]  = fmaxf(gamma[5] *v1.y + beta[5] , 0.f);
        t16[6]  = fmaxf(gamma[6] *v1.z + beta[6] , 0.f);
        t16[7]  = fmaxf(gamma[7] *v1.w + beta[7] , 0.f);
        t16[8]  = fmaxf(gamma[8] *v2.x + beta[8] , 0.f);
        t16[9]  = fmaxf(gamma[9] *v2.y + beta[9] , 0.f);
        t16[10] = fmaxf(gamma[10]*v2.z + beta[10], 0.f);
        t16[11] = fmaxf(gamma[11]*v2.w + beta[11], 0.f);
        t16[12] = fmaxf(gamma[12]*v3.x + beta[12], 0.f);
        t16[13] = fmaxf(gamma[13]*v3.y + beta[13], 0.f);
        t16[14] = fmaxf(gamma[14]*v3.z + beta[14], 0.f);
        t16[15] = fmaxf(gamma[15]*v3.w + beta[15], 0.f);

        const float* sw = spanw + g*784;   // k,r wave-uniform -> s_load
        const float* sb = spanb + g*49;
        const int k0 = wv ? (wv*12 + 1) : 0;
        #pragma unroll
        for (int j = 0; j < 12; ++j) {
            int k = k0 + j;
            float a = sb[k];
            #pragma unroll
            for (int r = 0; r < 16; ++r) a += sw[k*16 + r] * t16[r];
            wl[k][px] = a;
        }
        if (wv == 0) {
            float a = sb[12];
            #pragma unroll
            for (int r = 0; r < 16; ++r) a += sw[12*16 + r] * t16[r];
            wl[12][px] = a;
        }
    }
    __syncthreads();

    // ---- einsum: 49 taps x 4 channels (wave's quad), all LDS ----
    const int cq = wv;
    float4 acc = make_float4(0.f, 0.f, 0.f, 0.f);
    #pragma unroll
    for (int i = 0; i < 7; ++i)
        #pragma unroll
        for (int j = 0; j < 7; ++j) {
            float4 xv = *(const float4*)&xl[cq][sr + i][sc + j][0];
            float wk = wl[i*7 + j][px];
            acc.x += wk*xv.x; acc.y += wk*xv.y;
            acc.z += wk*xv.z; acc.w += wk*xv.w;
        }

    const int h = ty + sr, ww2 = tx + sc;
    const bool valid = (h < HH) && (ww2 < HH);
    float4 o = make_float4(fmaxf(acc.x,0.f), fmaxf(acc.y,0.f),
                           fmaxf(acc.z,0.f), fmaxf(acc.w,0.f));
    if (valid)
        *(float4*)(xout + (size_t)g*GP
                   + ((size_t)(h+3)*SP + (ww2+3))*16 + cq*4) = o;

    // ---- next-layer t partial: in-WG reduce via dead xl, plain stores -----
    if (doNext) {
        float* ol = (float*)xl;            // [64][17], 2-way banks
        __syncthreads();                   // einsum reads of xl done
        ol[px*17 + cq*4 + 0] = o.x;
        ol[px*17 + cq*4 + 1] = o.y;
        ol[px*17 + cq*4 + 2] = o.z;
        ol[px*17 + cq*4 + 3] = o.w;
        __syncthreads();
        // thread (px, rq = wv): partial t rows rq*4..+3 over group's 16 ch
        const int rq = wv;
        float p0=0.f, p1=0.f, p2=0.f, p3=0.f;
        #pragma unroll
        for (int j = 0; j < 16; ++j) {
            float xv = ol[px*17 + j];
            const int c = g*16 + j;        // wave-uniform -> s_load redwn
            p0 += redwn[(rq*4+0)*64 + c]*xv;
            p1 += redwn[(rq*4+1)*64 + c]*xv;
            p2 += redwn[(rq*4+2)*64 + c]*xv;
            p3 += redwn[(rq*4+3)*64 + c]*xv;
        }
        if (valid)
            *(float4*)(twrite + (size_t)g*TP1
                       + ((size_t)h*HH + ww2)*16 + rq*4) =
                make_float4(p0, p1, p2, p3);
    }
}

// --- conv_out (64->12, 3x3 valid) + PixelShuffle(2) ------------------------
__global__ __launch_bounds__(256) void conv_out_ps_kernel(
        const float* __restrict__ x, const float* __restrict__ W,
        const float* __restrict__ b, float* __restrict__ out)
{
    __shared__ float xh[64*120];   // [c][10 r][12 cl]
    __shared__ float wl[6912];     // 12*64*9
    const int tid = threadIdx.x;
    const int ty = blockIdx.y*8, tx = blockIdx.x*8;

    for (int idx = tid; idx < 6912; idx += 256) wl[idx] = W[idx];
    for (int idx = tid; idx < 1600; idx += 256) {
        int g = idx/400, rem = idx%400;
        int p100 = rem>>2, q = rem&3;
        int r = p100/10, cl = p100%10;
        float4 v = *(const float4*)(x + (size_t)g*GP
                     + ((size_t)(ty + r + 3)*SP + tx + cl + 3)*16 + q*4);
        int c0 = g*16 + q*4;
        xh[(c0+0)*120 + r*12 + cl] = v.x;
        xh[(c0+1)*120 + r*12 + cl] = v.y;
        xh[(c0+2)*120 + r*12 + cl] = v.z;
        xh[(c0+3)*120 + r*12 + cl] = v.w;
    }
    __syncthreads();

    const int wave = __builtin_amdgcn_readfirstlane(tid >> 6);
    const int lane = tid & 63;
    const int s = lane >> 2, cq = lane & 3;
    const int sr = s >> 1, pc0 = (s & 1)*4;
    float acc[3][4] = {};

    for (int c = cq*16; c < cq*16 + 16; ++c) {
        #pragma unroll
        for (int ky = 0; ky < 3; ++ky) {
            const float* xb = &xh[c*120 + (sr + ky)*12 + pc0];
            float4 xa = *(const float4*)xb;
            float2 xm = *(const float2*)(xb + 4);
            float xr[6] = {xa.x, xa.y, xa.z, xa.w, xm.x, xm.y};
            #pragma unroll
            for (int oj = 0; oj < 3; ++oj) {
                const float* wp = &wl[((wave*3 + oj)*64 + c)*9 + ky*3];
                #pragma unroll
                for (int kx = 0; kx < 3; ++kx) {
                    float wv = wp[kx];
                    #pragma unroll
                    for (int q = 0; q < 4; ++q)
                        acc[oj][q] += wv * xr[kx + q];
                }
            }
        }
    }

    #pragma unroll
    for (int oj = 0; oj < 3; ++oj)
        #pragma unroll
        for (int q = 0; q < 4; ++q) {
            float v = acc[oj][q];
            v += __shfl_xor(v, 1, 64);
            v += __shfl_xor(v, 2, 64);
            acc[oj][q] = v;
        }

    if (cq == 0) {
        #pragma unroll
        for (int oj = 0; oj < 3; ++oj) {
            int o = wave*3 + oj;
            float bo = b[o];
            int c3 = o >> 2, r = (o >> 1) & 1, s2 = o & 1;
            int h = ty + sr;
            #pragma unroll
            for (int q = 0; q < 4; ++q) {
                int w = tx + pc0 + q;
                out[c3*65536 + (2*h + r)*256 + 2*w + s2] = acc[oj][q] + bo;
            }
        }
    }
}

// ---------------------------------------------------------------------------
extern "C" void kernel_launch(void* const* d_in, const int* in_sizes, int n_in,
                              void* d_out, int out_size, void* d_ws, size_t ws_size,
                              hipStream_t stream) {
    const float* inf   = (const float*)d_in[0];
    const float* cinw  = (const float*)d_in[1];
    const float* cinb  = (const float*)d_in[2];
    const float* redw  = (const float*)d_in[3];
    const float* gam   = (const float*)d_in[4];
    const float* bet   = (const float*)d_in[5];
    const float* spw   = (const float*)d_in[6];
    const float* spb   = (const float*)d_in[7];
    const float* cow   = (const float*)d_in[8];
    const float* cob   = (const float*)d_in[9];

    float* ws = (float*)d_ws;
    float* x0 = ws;
    float* x1 = ws + XBUF2;
    float* tA = ws + OFF_TA;
    float* tB = ws + OFF_TB;

    conv_in_kernel<<<dim3(80, 4), 256, 0, stream>>>(
        inf, cinw, cinb, x0, x1, tA, redw);

    float* cur = x0; float* nxt = x1;
    for (int l = 0; l < 6; ++l) {
        const int doNext = (l < 5);
        float* tread  = (l & 1) ? tB : tA;
        float* twrite = (l & 1) ? tA : tB;
        e_kernel<<<1184, 256, 0, stream>>>(
            cur, tread, twrite,
            gam + l*16, bet + l*16,
            spw + l*3136, spb + l*196,
            redw + (doNext ? (l+1)*1024 : 0),
            nxt, doNext);
        float* t = cur; cur = nxt; nxt = t;
    }

    conv_out_ps_kernel<<<dim3(16, 16), 256, 0, stream>>>(
        cur, cow, cob, (float*)d_out);
}

// Round 15
// 190.910 us; speedup vs baseline: 7.2683x; 1.0098x over previous
//
#include <hip/hip_runtime.h>

// ---------------------------------------------------------------------------
// ZSSR involution net, fp32. Round 15 = R14 (192.8us) + e-internal fixes:
//  (a) 5 WGs/CU (launch_bounds(256,5); LDS 28.56KB -> 160/28.56 = 5.6, VGPR 44
//      << 102 cap; 1184 WGs <= 1280 resident => no tail wave).
//  (b) t-partial read dedup: thread (px,wv) reads r-quad wv of all 4 group
//      partials (4 float4, not 16), sums -> LDS tl (ALIASED over dead wl
//      region, no LDS growth), threads read t16 back via b128. 2 extra
//      intra-WG barriers, -12 VMEM instr/thread at dispatch start.
// Structure/grids/band-swizzle identical to R14. Dispatches: 8.
// Layout: x[4 g][136x136 px][16 ch] channel-last, 3-px zero border.
// ---------------------------------------------------------------------------

#define HH 130
#define SP 136               // padded row stride
#define PPL (SP*SP)          // 18496
#define GP (PPL*16)          // floats per group-plane
#define XBUF2 (4*GP)         // floats per feature buffer
#define TP1 (16900*16)       // one group-partial buffer [px][16]
#define OFF_TA (2*XBUF2)             // set A: 4 buffers
#define OFF_TB (OFF_TA + 4*TP1)      // set B: 4 buffers

// --- conv_in (3->64, 3x3, pad=2) + border zeroing + layer-0 t partials -----
__global__ __launch_bounds__(256) void conv_in_kernel(
        const float* __restrict__ inf, const float* __restrict__ W,
        const float* __restrict__ b, float* __restrict__ x0,
        float* __restrict__ x1, float* __restrict__ tpA,
        const float* __restrict__ redw0) {   // [16][64] layer 0
    const int tid = threadIdx.x;
    if (blockIdx.x >= 67) {
        int idx = ((blockIdx.x - 67)*4 + blockIdx.y)*256 + tid;
        if (idx < 3192) {                      // 1596 border px * 2 buffers
            int bsel = idx & 1, e = idx >> 1;
            int r, c;
            if (e < 816) { r = e/136; c = e%136; if (r >= 3) r += 130; }
            else { int j = e-816; r = 3 + j/6; int m = j%6; c = (m<3)? m : m+130; }
            float* base = (bsel ? x1 : x0) + ((size_t)r*SP + c)*16;
            float4 z = make_float4(0.f,0.f,0.f,0.f);
            #pragma unroll
            for (int g2 = 0; g2 < 4; ++g2)
                #pragma unroll
                for (int q = 0; q < 4; ++q)
                    *(float4*)(base + (size_t)g2*GP + q*4) = z;
        }
        return;
    }
    __shared__ float wl[448];          // [16 ch][27 taps] + bias[16]
    const int g = blockIdx.y;
    for (int i = tid; i < 448; i += 256)
        wl[i] = (i < 432) ? W[g*432 + i] : b[g*16 + (i-432)];
    __syncthreads();
    int px = blockIdx.x*256 + tid;
    int pxc = px < 16900 ? px : 16899;
    int h = pxc/130, w = pxc%130;
    float xv[27];
    #pragma unroll
    for (int i = 0; i < 3; ++i)
      #pragma unroll
      for (int ky = 0; ky < 3; ++ky) {
        int y = h - 2 + ky;
        #pragma unroll
        for (int kx = 0; kx < 3; ++kx) {
            int xx = w - 2 + kx;
            float v = 0.f;
            if ((unsigned)y < 128u && (unsigned)xx < 128u)
                v = inf[i*16384 + y*128 + xx];
            xv[i*9 + ky*3 + kx] = v;
        }
      }
    float acc[16];
    #pragma unroll
    for (int c = 0; c < 16; ++c) {
        float a = wl[432 + c];
        #pragma unroll
        for (int t = 0; t < 27; ++t) a += wl[c*27 + t] * xv[t];
        acc[c] = a;
    }
    if (px < 16900) {
        float* dst = x0 + (size_t)g*GP + ((size_t)(h+3)*SP + (w+3))*16;
        #pragma unroll
        for (int q = 0; q < 4; ++q)
            *(float4*)(dst + q*4) =
                make_float4(acc[q*4], acc[q*4+1], acc[q*4+2], acc[q*4+3]);
        // layer-0 t partial for group g (thread owns all 16 ch; s_load redw0)
        float* td = tpA + (size_t)g*TP1 + (size_t)px*16;
        #pragma unroll
        for (int rq = 0; rq < 4; ++rq) {
            float p0=0.f, p1=0.f, p2=0.f, p3=0.f;
            #pragma unroll
            for (int j = 0; j < 16; ++j) {
                float a = acc[j];
                p0 += redw0[(rq*4+0)*64 + g*16 + j]*a;
                p1 += redw0[(rq*4+1)*64 + g*16 + j]*a;
                p2 += redw0[(rq*4+2)*64 + g*16 + j]*a;
                p3 += redw0[(rq*4+3)*64 + g*16 + j]*a;
            }
            *(float4*)(td + rq*4) = make_float4(p0, p1, p2, p3);
        }
    }
}

// --- e_kernel v11 = R14 v10 + t-read dedup + 5 WGs/CU ----------------------
// grid 1184: wid&7 = band, slot = wid>>3; T = band*37+(slot>>2), g = slot&3.
// LDS: xl[4][14][17][4] 15232B + uu (tl[64][20] ALIAS wl[49][68]) 13328B
//    = 28560B -> 5 WG/CU at launch_bounds(256,5).
#define TL(p, r)  uu[(p)*20 + (r)]
#define WLK(k, p) uu[(k)*68 + (p)]
__global__ __launch_bounds__(256, 5) void e_kernel(
        const float* __restrict__ x,
        const float* __restrict__ tread,  // 4 partial bufs, this layer
        float* __restrict__ twrite,       // 4 partial bufs, next layer
        const float* __restrict__ gamma, const float* __restrict__ beta,
        const float* __restrict__ spanw,  // [4 g][49 k][16 r]
        const float* __restrict__ spanb,  // [4 g][49]
        const float* __restrict__ redwn,  // [16][64] next layer
        float* __restrict__ xout,
        const int doNext)
{
    __shared__ float xl[4][14][17][4];
    __shared__ float uu[49*68];           // tl (phase 1) then wl (phase 2)
    const int wid = blockIdx.x;
    const int slot = wid >> 3;
    const int T = (wid & 7)*37 + (slot >> 2);
    if (T >= 289) return;
    const int g = slot & 3;
    const int ty = (T/17)*8, tx = (T%17)*8;
    const int tid = threadIdx.x;
    const int px = tid & 63;
    const int wv = __builtin_amdgcn_readfirstlane(tid >> 6);
    const int sr = px >> 3, sc = px & 7;

    // ---- stage halo: 14x14 px, 4 quads (group g's 16 ch) ----
    for (int i = tid; i < 784; i += 256) {
        int q = i & 3, p = i >> 2;
        int r = p / 14, c = p % 14;
        int gr = ty + r, gc = tx + c;
        gr = gr < SP ? gr : SP-1;          // clamp lands in zero border
        gc = gc < SP ? gc : SP-1;
        float4 v = *(const float4*)(x + (size_t)g*GP
                                    + ((size_t)gr*SP + gc)*16 + q*4);
        *(float4*)&xl[q][r][c][0] = v;
    }

    // ---- t dedup: thread (px,wv) sums r-quad wv across the 4 partials ----
    const int hh = min(ty + sr, HH-1), ww = min(tx + sc, HH-1);
    {
        const size_t toff = ((size_t)hh*HH + ww)*16 + wv*4;
        float4 s = make_float4(0.f,0.f,0.f,0.f);
        #pragma unroll
        for (int gg = 0; gg < 4; ++gg) {
            float4 a = *(const float4*)(tread + (size_t)gg*TP1 + toff);
            s.x += a.x; s.y += a.y; s.z += a.z; s.w += a.w;
        }
        *(float4*)&TL(px, wv*4) = s;       // raw sums (BN applied on read)
    }
    __syncthreads();                       // #1: tl complete

    // ---- read t16 (BN+ReLU) ----
    float t16[16];
    #pragma unroll
    for (int q = 0; q < 4; ++q) {
        float4 v = *(const float4*)&TL(px, q*4);
        t16[q*4+0] = fmaxf(gamma[q*4+0]*v.x + beta[q*4+0], 0.f);
        t16[q*4+1] = fmaxf(gamma[q*4+1]*v.y + beta[q*4+1], 0.f);
        t16[q*4+2] = fmaxf(gamma[q*4+2]*v.z + beta[q*4+2], 0.f);
        t16[q*4+3] = fmaxf(gamma[q*4+3]*v.w + beta[q*4+3], 0.f);
    }
    __syncthreads();                       // #2: tl reads done, wl may write

    // ---- w-gen: lane = pixel, wave = k-chunk (13/12/12/12) ----
    {
        const float* sw = spanw + g*784;   // k,r wave-uniform -> s_load
        const float* sb = spanb + g*49;
        const int k0 = wv ? (wv*12 + 1) : 0;
        #pragma unroll
        for (int j = 0; j < 12; ++j) {
            int k = k0 + j;
            float a = sb[k];
            #pragma unroll
            for (int r = 0; r < 16; ++r) a += sw[k*16 + r] * t16[r];
            WLK(k, px) = a;
        }
        if (wv == 0) {
            float a = sb[12];
            #pragma unroll
            for (int r = 0; r < 16; ++r) a += sw[12*16 + r] * t16[r];
            WLK(12, px) = a;
        }
    }
    __syncthreads();                       // #3: wl complete (and halo in xl)

    // ---- einsum: 49 taps x 4 channels (wave's quad), all LDS ----
    const int cq = wv;
    float4 acc = make_float4(0.f, 0.f, 0.f, 0.f);
    #pragma unroll
    for (int i = 0; i < 7; ++i)
        #pragma unroll
        for (int j = 0; j < 7; ++j) {
            float4 xv = *(const float4*)&xl[cq][sr + i][sc + j][0];
            float wk = WLK(i*7 + j, px);
            acc.x += wk*xv.x; acc.y += wk*xv.y;
            acc.z += wk*xv.z; acc.w += wk*xv.w;
        }

    const int h = ty + sr, ww2 = tx + sc;
    const bool valid = (h < HH) && (ww2 < HH);
    float4 o = make_float4(fmaxf(acc.x,0.f), fmaxf(acc.y,0.f),
                           fmaxf(acc.z,0.f), fmaxf(acc.w,0.f));
    if (valid)
        *(float4*)(xout + (size_t)g*GP
                   + ((size_t)(h+3)*SP + (ww2+3))*16 + cq*4) = o;

    // ---- next-layer t partial: in-WG reduce via dead xl, plain stores -----
    if (doNext) {
        float* ol = (float*)xl;            // [64][17], 2-way banks
        __syncthreads();                   // einsum reads of xl done
        ol[px*17 + cq*4 + 0] = o.x;
        ol[px*17 + cq*4 + 1] = o.y;
        ol[px*17 + cq*4 + 2] = o.z;
        ol[px*17 + cq*4 + 3] = o.w;
        __syncthreads();
        // thread (px, rq = wv): partial t rows rq*4..+3 over group's 16 ch
        const int rq = wv;
        float p0=0.f, p1=0.f, p2=0.f, p3=0.f;
        #pragma unroll
        for (int j = 0; j < 16; ++j) {
            float xv = ol[px*17 + j];
            const int c = g*16 + j;        // wave-uniform -> s_load redwn
            p0 += redwn[(rq*4+0)*64 + c]*xv;
            p1 += redwn[(rq*4+1)*64 + c]*xv;
            p2 += redwn[(rq*4+2)*64 + c]*xv;
            p3 += redwn[(rq*4+3)*64 + c]*xv;
        }
        if (valid)
            *(float4*)(twrite + (size_t)g*TP1
                       + ((size_t)h*HH + ww2)*16 + rq*4) =
                make_float4(p0, p1, p2, p3);
    }
}

// --- conv_out (64->12, 3x3 valid) + PixelShuffle(2) ------------------------
__global__ __launch_bounds__(256) void conv_out_ps_kernel(
        const float* __restrict__ x, const float* __restrict__ W,
        const float* __restrict__ b, float* __restrict__ out)
{
    __shared__ float xh[64*120];   // [c][10 r][12 cl]
    __shared__ float wl[6912];     // 12*64*9
    const int tid = threadIdx.x;
    const int ty = blockIdx.y*8, tx = blockIdx.x*8;

    for (int idx = tid; idx < 6912; idx += 256) wl[idx] = W[idx];
    for (int idx = tid; idx < 1600; idx += 256) {
        int g = idx/400, rem = idx%400;
        int p100 = rem>>2, q = rem&3;
        int r = p100/10, cl = p100%10;
        float4 v = *(const float4*)(x + (size_t)g*GP
                     + ((size_t)(ty + r + 3)*SP + tx + cl + 3)*16 + q*4);
        int c0 = g*16 + q*4;
        xh[(c0+0)*120 + r*12 + cl] = v.x;
        xh[(c0+1)*120 + r*12 + cl] = v.y;
        xh[(c0+2)*120 + r*12 + cl] = v.z;
        xh[(c0+3)*120 + r*12 + cl] = v.w;
    }
    __syncthreads();

    const int wave = __builtin_amdgcn_readfirstlane(tid >> 6);
    const int lane = tid & 63;
    const int s = lane >> 2, cq = lane & 3;
    const int sr = s >> 1, pc0 = (s & 1)*4;
    float acc[3][4] = {};

    for (int c = cq*16; c < cq*16 + 16; ++c) {
        #pragma unroll
        for (int ky = 0; ky < 3; ++ky) {
            const float* xb = &xh[c*120 + (sr + ky)*12 + pc0];
            float4 xa = *(const float4*)xb;
            float2 xm = *(const float2*)(xb + 4);
            float xr[6] = {xa.x, xa.y, xa.z, xa.w, xm.x, xm.y};
            #pragma unroll
            for (int oj = 0; oj < 3; ++oj) {
                const float* wp = &wl[((wave*3 + oj)*64 + c)*9 + ky*3];
                #pragma unroll
                for (int kx = 0; kx < 3; ++kx) {
                    float wv = wp[kx];
                    #pragma unroll
                    for (int q = 0; q < 4; ++q)
                        acc[oj][q] += wv * xr[kx + q];
                }
            }
        }
    }

    #pragma unroll
    for (int oj = 0; oj < 3; ++oj)
        #pragma unroll
        for (int q = 0; q < 4; ++q) {
            float v = acc[oj][q];
            v += __shfl_xor(v, 1, 64);
            v += __shfl_xor(v, 2, 64);
            acc[oj][q] = v;
        }

    if (cq == 0) {
        #pragma unroll
        for (int oj = 0; oj < 3; ++oj) {
            int o = wave*3 + oj;
            float bo = b[o];
            int c3 = o >> 2, r = (o >> 1) & 1, s2 = o & 1;
            int h = ty + sr;
            #pragma unroll
            for (int q = 0; q < 4; ++q) {
                int w = tx + pc0 + q;
                out[c3*65536 + (2*h + r)*256 + 2*w + s2] = acc[oj][q] + bo;
            }
        }
    }
}

// ---------------------------------------------------------------------------
extern "C" void kernel_launch(void* const* d_in, const int* in_sizes, int n_in,
                              void* d_out, int out_size, void* d_ws, size_t ws_size,
                              hipStream_t stream) {
    const float* inf   = (const float*)d_in[0];
    const float* cinw  = (const float*)d_in[1];
    const float* cinb  = (const float*)d_in[2];
    const float* redw  = (const float*)d_in[3];
    const float* gam   = (const float*)d_in[4];
    const float* bet   = (const float*)d_in[5];
    const float* spw   = (const float*)d_in[6];
    const float* spb   = (const float*)d_in[7];
    const float* cow   = (const float*)d_in[8];
    const float* cob   = (const float*)d_in[9];

    float* ws = (float*)d_ws;
    float* x0 = ws;
    float* x1 = ws + XBUF2;
    float* tA = ws + OFF_TA;
    float* tB = ws + OFF_TB;

    conv_in_kernel<<<dim3(80, 4), 256, 0, stream>>>(
        inf, cinw, cinb, x0, x1, tA, redw);

    float* cur = x0; float* nxt = x1;
    for (int l = 0; l < 6; ++l) {
        const int doNext = (l < 5);
        float* tread  = (l & 1) ? tB : tA;
        float* twrite = (l & 1) ? tA : tB;
        e_kernel<<<1184, 256, 0, stream>>>(
            cur, tread, twrite,
            gam + l*16, bet + l*16,
            spw + l*3136, spb + l*196,
            redw + (doNext ? (l+1)*1024 : 0),
            nxt, doNext);
        float* t = cur; cur = nxt; nxt = t;
    }

    conv_out_ps_kernel<<<dim3(16, 16), 256, 0, stream>>>(
        cur, cow, cob, (float*)d_out);
}